// Round 13
// baseline (505.830 us; speedup 1.0000x reference)
//
#include <hip/hip_runtime.h>

#define NN 50000
#define NE 1600000
#define GG 512
#define PAD 96
#define NBKT 196
#define BCAP 12288
#define CHUNK 6250
#define NBLK_MLP 782
#define NRED1 196
#define BN_EPS 1e-5f
#define XCONV_TOT (NN * 32)
#define NTRB 96   // transpose blocks: 24 (W) + 72 (Wp)

typedef __attribute__((ext_vector_type(8))) short short8;
typedef __attribute__((ext_vector_type(4))) float f32x4;

__device__ __forceinline__ unsigned short f2bf(float x) {
    unsigned int u = __builtin_bit_cast(unsigned int, x);
    return (unsigned short)((u + 0x7FFFu + ((u >> 16) & 1u)) >> 16);
}
__device__ __forceinline__ float bf2f(unsigned int b) {
    return __builtin_bit_cast(float, b << 16);
}

// ---------------- phase 1: bucket edges by dst>>8 into staging ---------------
__global__ __launch_bounds__(256) void bucket_k(const int* __restrict__ src, const int* __restrict__ dst,
                                                int* __restrict__ bcur, unsigned int* __restrict__ staging) {
    __shared__ int hist[NBKT];
    __shared__ int curs[NBKT];
    const int t = threadIdx.x;
    if (t < NBKT) hist[t] = 0;
    __syncthreads();
    const int e0 = blockIdx.x * CHUNK;
    const int e1 = e0 + CHUNK;
    for (int e = e0 + t; e < e1; e += 256) atomicAdd(&hist[dst[e] >> 8], 1);
    __syncthreads();
    if (t < NBKT) {
        int c = hist[t];
        curs[t] = (c > 0) ? atomicAdd(&bcur[t], c) : 0;
    }
    __syncthreads();
    for (int e = e0 + t; e < e1; e += 256) {
        int d = dst[e];
        int b = d >> 8;
        int pos = atomicAdd(&curs[b], 1);
        staging[(size_t)b * BCAP + pos] = (unsigned int)(d & 255) | ((unsigned int)src[e] << 8);
    }
}

// ---------------- phase 2: bucket -> LDS ELL tile -> coalesced global --------
__global__ __launch_bounds__(256) void ellfill_k(const int* __restrict__ bcur,
                                                 const unsigned int* __restrict__ staging,
                                                 int* __restrict__ cnt, unsigned short* __restrict__ ell) {
    __shared__ unsigned short lell[256 * PAD]; // 48 KB
    __shared__ int lcnt[256];
    const int b = blockIdx.x, t = threadIdx.x;
    lcnt[t] = 0;
    __syncthreads();
    const int tot = bcur[b];
    const unsigned int* sg = staging + (size_t)b * BCAP;
    for (int i = t; i < tot; i += 256) {
        unsigned int v = sg[i];
        int r = v & 255;
        int p = atomicAdd(&lcnt[r], 1);
        lell[r * PAD + p] = (unsigned short)(v >> 8);
    }
    __syncthreads();
    const int n0 = b << 8;
    const int nrows = min(256, NN - n0);
    for (int i = t; i < nrows * 12; i += 256) {
        int r = i / 12, q = i % 12;
        *(uint4*)(ell + (size_t)(n0 + r) * PAD + q * 8) = *(const uint4*)(lell + r * PAD + q * 8);
    }
    if (t < nrows) cnt[n0 + t] = lcnt[t];
}

// ---------------- conversions: tiled W/Wp transposes + x->bf16 + bcur zero ---
__global__ __launch_bounds__(256) void conv_k(const float* __restrict__ x,
                                              const float* __restrict__ W1, const float* __restrict__ W2,
                                              const float* __restrict__ Wp1, const float* __restrict__ Wp2,
                                              unsigned short* __restrict__ xb, unsigned short* __restrict__ Wt,
                                              unsigned short* __restrict__ Wpt, int* __restrict__ bcur) {
    const int b = blockIdx.x, tid = threadIdx.x;
    if (b < NTRB) {
        __shared__ float tile[64 * 65];
        const float* S;
        unsigned short* D;
        int srcW, dstW, k0, c0;
        if (b < 24) {                       // W: 6 mats x (2x2 64-tiles), 128x128
            int mat = b >> 2, t = b & 3;
            S = ((mat & 1) ? W2 : W1) + (size_t)(mat >> 1) * 16384;
            D = Wt + (size_t)mat * 16384;
            srcW = 128; dstW = 128;
            k0 = (t >> 1) * 64; c0 = (t & 1) * 64;
        } else {                            // Wp: 2 mats x (6x6 64-tiles), 384x384
            int bb = b - 24;
            int mat = bb / 36, t = bb % 36;
            S = mat ? Wp2 : Wp1;
            D = Wpt + (size_t)mat * 147456;
            srcW = 384; dstW = 384;
            k0 = (t / 6) * 64; c0 = (t % 6) * 64;
        }
        for (int idx = tid; idx < 4096; idx += 256) {
            int r = idx >> 6, c = idx & 63;
            tile[r * 65 + c] = S[(size_t)(k0 + r) * srcW + c0 + c];
        }
        __syncthreads();
        for (int idx = tid; idx < 4096; idx += 256) {
            int r = idx >> 6, c = idx & 63;   // out row r = c-dim, out col c = k-dim
            D[(size_t)(c0 + r) * dstW + k0 + c] = f2bf(tile[c * 65 + r]);
        }
    } else {
        int i = (b - NTRB) * 256 + tid;
        if (i < NBKT) bcur[i] = 0;
        const int stp = (gridDim.x - NTRB) * 256;
        for (; i < XCONV_TOT; i += stp) {
            float4 v = ((const float4*)x)[i];
            uint2 pk;
            pk.x = (unsigned int)f2bf(v.x) | ((unsigned int)f2bf(v.y) << 16);
            pk.y = (unsigned int)f2bf(v.z) | ((unsigned int)f2bf(v.w) << 16);
            ((uint2*)xb)[i] = pk;
        }
    }
}

// ---------------- fused layer: agg(LDS) -> GEMM1 -> GEMM2 -> y + stats ------
// Per block: 64 rows. sA holds agg result, then T-tile, then stats-reduce.
__global__ __launch_bounds__(256) void layer_k(const int* __restrict__ cnt, const unsigned short* __restrict__ ell,
                                               const unsigned short* __restrict__ h, const float* __restrict__ ss,
                                               const unsigned short* __restrict__ Wt,
                                               const float* __restrict__ bias1, const float* __restrict__ bias2,
                                               unsigned short* __restrict__ yb, float* __restrict__ scr) {
    __shared__ __align__(16) unsigned short sW[128 * 136];  // 34 KB
    __shared__ __align__(16) unsigned short sA[64 * 136];   // 17 KB (agg -> T -> sred)
    float* sred = (float*)sA;
    const int tid = threadIdx.x;
    const int row0 = blockIdx.x * 64;
    // load W1 into sW
    for (int ch = tid; ch < 2048; ch += 256) {
        int c = ch >> 4, i = ch & 15;
        *(uint4*)(sW + c * 136 + i * 8) = *(const uint4*)(Wt + c * 128 + i * 8);
    }
    // ---- aggregation phase: 4 passes x 16 nodes, 16 lanes/node ----
    {
        const int l = tid & 15;
        float sc[8], sh[8];
        #pragma unroll
        for (int j = 0; j < 8; ++j) { sc[j] = 1.f; sh[j] = 0.f; }
        if (ss) {
            #pragma unroll
            for (int j = 0; j < 8; ++j) { sc[j] = ss[l * 8 + j]; sh[j] = ss[128 + l * 8 + j]; }
        }
        #pragma unroll
        for (int pass = 0; pass < 4; ++pass) {
            int lrow = pass * 16 + (tid >> 4);
            int n = row0 + lrow;
            uint4 pk = {0u, 0u, 0u, 0u};
            if (n < NN) {
                int e = cnt[n];
                const unsigned short* row = ell + (size_t)n * PAD;
                float acc[8];
                {
                    uint4 q = *(const uint4*)(h + (size_t)n * 128 + l * 8);
                    unsigned int qq[4] = {q.x, q.y, q.z, q.w};
                    #pragma unroll
                    for (int j = 0; j < 4; ++j) {
                        acc[2 * j]     = bf2f(qq[j] & 0xffffu) * sc[2 * j];
                        acc[2 * j + 1] = bf2f(qq[j] >> 16)     * sc[2 * j + 1];
                    }
                }
                int i = 0;
                for (; i + 8 <= e; i += 8) {
                    uint4 ip = *(const uint4*)(row + i);
                    int s0 = ip.x & 0xffff, s1 = ip.x >> 16, s2 = ip.y & 0xffff, s3 = ip.y >> 16;
                    int s4 = ip.z & 0xffff, s5 = ip.z >> 16, s6 = ip.w & 0xffff, s7 = ip.w >> 16;
                    uint4 q0 = *(const uint4*)(h + (size_t)s0 * 128 + l * 8);
                    uint4 q1 = *(const uint4*)(h + (size_t)s1 * 128 + l * 8);
                    uint4 q2 = *(const uint4*)(h + (size_t)s2 * 128 + l * 8);
                    uint4 q3 = *(const uint4*)(h + (size_t)s3 * 128 + l * 8);
                    uint4 q4 = *(const uint4*)(h + (size_t)s4 * 128 + l * 8);
                    uint4 q5 = *(const uint4*)(h + (size_t)s5 * 128 + l * 8);
                    uint4 q6 = *(const uint4*)(h + (size_t)s6 * 128 + l * 8);
                    uint4 q7 = *(const uint4*)(h + (size_t)s7 * 128 + l * 8);
                    unsigned int a0[4] = {q0.x, q0.y, q0.z, q0.w};
                    unsigned int a1[4] = {q1.x, q1.y, q1.z, q1.w};
                    unsigned int a2[4] = {q2.x, q2.y, q2.z, q2.w};
                    unsigned int a3[4] = {q3.x, q3.y, q3.z, q3.w};
                    unsigned int a4[4] = {q4.x, q4.y, q4.z, q4.w};
                    unsigned int a5[4] = {q5.x, q5.y, q5.z, q5.w};
                    unsigned int a6[4] = {q6.x, q6.y, q6.z, q6.w};
                    unsigned int a7[4] = {q7.x, q7.y, q7.z, q7.w};
                    #pragma unroll
                    for (int j = 0; j < 4; ++j) {
                        float t0 = bf2f(a0[j] & 0xffffu) + bf2f(a1[j] & 0xffffu);
                        float t1 = bf2f(a2[j] & 0xffffu) + bf2f(a3[j] & 0xffffu);
                        float t2 = bf2f(a4[j] & 0xffffu) + bf2f(a5[j] & 0xffffu);
                        float t3 = bf2f(a6[j] & 0xffffu) + bf2f(a7[j] & 0xffffu);
                        acc[2*j] = fmaf((t0 + t1) + (t2 + t3), sc[2*j], acc[2*j]);
                        float u0 = bf2f(a0[j] >> 16) + bf2f(a1[j] >> 16);
                        float u1 = bf2f(a2[j] >> 16) + bf2f(a3[j] >> 16);
                        float u2 = bf2f(a4[j] >> 16) + bf2f(a5[j] >> 16);
                        float u3 = bf2f(a6[j] >> 16) + bf2f(a7[j] >> 16);
                        acc[2*j+1] = fmaf((u0 + u1) + (u2 + u3), sc[2*j+1], acc[2*j+1]);
                    }
                }
                for (; i < e; ++i) {
                    int s0 = row[i];
                    uint4 q = *(const uint4*)(h + (size_t)s0 * 128 + l * 8);
                    unsigned int qq[4] = {q.x, q.y, q.z, q.w};
                    #pragma unroll
                    for (int j = 0; j < 4; ++j) {
                        acc[2*j]   = fmaf(bf2f(qq[j] & 0xffffu), sc[2*j],   acc[2*j]);
                        acc[2*j+1] = fmaf(bf2f(qq[j] >> 16),     sc[2*j+1], acc[2*j+1]);
                    }
                }
                float fe = (float)(e + 1);
                #pragma unroll
                for (int j = 0; j < 8; ++j) acc[j] = fmaf(fe, sh[j], acc[j]);
                pk.x = (unsigned int)f2bf(acc[0]) | ((unsigned int)f2bf(acc[1]) << 16);
                pk.y = (unsigned int)f2bf(acc[2]) | ((unsigned int)f2bf(acc[3]) << 16);
                pk.z = (unsigned int)f2bf(acc[4]) | ((unsigned int)f2bf(acc[5]) << 16);
                pk.w = (unsigned int)f2bf(acc[6]) | ((unsigned int)f2bf(acc[7]) << 16);
            }
            *(uint4*)(sA + lrow * 136 + l * 8) = pk;
        }
    }
    __syncthreads();   // barrier1: sA (agg) + sW (W1) ready
    const int w = tid >> 6, l = tid & 63;
    const int lr = l & 15, lk = l >> 4;
    const unsigned short* ap = sA + (w * 16 + lr) * 136 + lk * 8;
    short8 af0 = *(const short8*)(ap);
    short8 af1 = *(const short8*)(ap + 32);
    short8 af2 = *(const short8*)(ap + 64);
    short8 af3 = *(const short8*)(ap + 96);
    __syncthreads();   // barrier2: all sA reads done -> epilogue1 may overwrite
    f32x4 acc[8] = {};
    #pragma unroll
    for (int c = 0; c < 8; ++c) {
        const unsigned short* wp = sW + (c * 16 + lr) * 136 + lk * 8;
        short8 wf0 = *(const short8*)(wp);
        short8 wf1 = *(const short8*)(wp + 32);
        short8 wf2 = *(const short8*)(wp + 64);
        short8 wf3 = *(const short8*)(wp + 96);
        acc[c] = __builtin_amdgcn_mfma_f32_16x16x32_bf16(af0, wf0, acc[c], 0, 0, 0);
        acc[c] = __builtin_amdgcn_mfma_f32_16x16x32_bf16(af1, wf1, acc[c], 0, 0, 0);
        acc[c] = __builtin_amdgcn_mfma_f32_16x16x32_bf16(af2, wf2, acc[c], 0, 0, 0);
        acc[c] = __builtin_amdgcn_mfma_f32_16x16x32_bf16(af3, wf3, acc[c], 0, 0, 0);
    }
    const int lrow = w * 16 + lk * 4;
    #pragma unroll
    for (int c = 0; c < 8; ++c) {
        int col = c * 16 + lr;
        float b = bias1[col];
        #pragma unroll
        for (int r = 0; r < 4; ++r) {
            float v = fmaxf(acc[c][r] + b, 0.f);
            sA[(lrow + r) * 136 + col] = f2bf(v);
        }
    }
    __syncthreads();   // barrier3: T complete, W1 reads complete
    for (int ch = tid; ch < 2048; ch += 256) {
        int c = ch >> 4, i = ch & 15;
        *(uint4*)(sW + c * 136 + i * 8) = *(const uint4*)(Wt + 16384 + c * 128 + i * 8);
    }
    const unsigned short* tp = sA + (w * 16 + lr) * 136 + lk * 8;
    short8 bf0 = *(const short8*)(tp);
    short8 bf1 = *(const short8*)(tp + 32);
    short8 bf2_ = *(const short8*)(tp + 64);
    short8 bf3 = *(const short8*)(tp + 96);
    f32x4 acc2[8] = {};
    __syncthreads();   // barrier4: sW (W2) ready, all T reads done
    #pragma unroll
    for (int c = 0; c < 8; ++c) {
        const unsigned short* wp = sW + (c * 16 + lr) * 136 + lk * 8;
        short8 wf0 = *(const short8*)(wp);
        short8 wf1 = *(const short8*)(wp + 32);
        short8 wf2 = *(const short8*)(wp + 64);
        short8 wf3 = *(const short8*)(wp + 96);
        acc2[c] = __builtin_amdgcn_mfma_f32_16x16x32_bf16(bf0, wf0, acc2[c], 0, 0, 0);
        acc2[c] = __builtin_amdgcn_mfma_f32_16x16x32_bf16(bf1, wf1, acc2[c], 0, 0, 0);
        acc2[c] = __builtin_amdgcn_mfma_f32_16x16x32_bf16(bf2_, wf2, acc2[c], 0, 0, 0);
        acc2[c] = __builtin_amdgcn_mfma_f32_16x16x32_bf16(bf3, wf3, acc2[c], 0, 0, 0);
    }
    const int drow = row0 + lk * 4 + w * 16;
    #pragma unroll
    for (int c = 0; c < 8; ++c) {
        int col = c * 16 + lr;
        float b = bias2[col];
        float s1 = 0.f, s2 = 0.f;
        #pragma unroll
        for (int r = 0; r < 4; ++r) {
            int grow = drow + r;
            float v = fmaxf(acc2[c][r] + b, 0.f);
            if (grow < NN) {
                yb[(size_t)grow * 128 + col] = f2bf(v);
                s1 += v;
                s2 += v * v;
            }
        }
        s1 += __shfl_xor(s1, 16); s1 += __shfl_xor(s1, 32);
        s2 += __shfl_xor(s2, 16); s2 += __shfl_xor(s2, 32);
        if (lk == 0) {
            sred[((w * 16 + lr) * 8 + c) * 2 + 0] = s1;   // sA free: all T reads pre-barrier4
            sred[((w * 16 + lr) * 8 + c) * 2 + 1] = s2;
        }
    }
    __syncthreads();
    int st = tid & 1, c = (tid >> 1) & 7, lr2 = tid >> 4;
    float t = 0.f;
    #pragma unroll
    for (int w2 = 0; w2 < 4; ++w2) t += sred[((w2 * 16 + lr2) * 8 + c) * 2 + st];
    scr[(size_t)blockIdx.x * 256 + st * 128 + c * 16 + lr2] = t;
}

// ---------------- BN reduce stage 1: scr[NBLK_MLP][256] -> part[NRED1][256] --
__global__ __launch_bounds__(256) void bnr1_k(const float* __restrict__ scr, float* __restrict__ part) {
    int b = blockIdx.x, d = threadIdx.x;
    float a = 0.f;
    for (int r = b; r < NBLK_MLP; r += NRED1) a += scr[(size_t)r * 256 + d];
    part[(size_t)b * 256 + d] = a;
}

// ---------------- BN reduce stage 2 + finalize -------------------------------
__global__ __launch_bounds__(1024) void bnr2_k(const float* __restrict__ part, const float* __restrict__ gamma,
                                               const float* __restrict__ beta, float* __restrict__ ss) {
    __shared__ float red[4][256];
    int t = threadIdx.x, q = t >> 8, d = t & 255;
    float a = 0.f;
    for (int r = q; r < NRED1; r += 4) a += part[(size_t)r * 256 + d];
    red[q][d] = a;
    __syncthreads();
    if (t < 256) red[0][t] = red[0][t] + red[1][t] + red[2][t] + red[3][t];
    __syncthreads();
    if (t < 128) {
        float mu = red[0][t] * (1.0f / NN);
        float var = red[0][128 + t] * (1.0f / NN) - mu * mu;
        float sc = gamma[t] * rsqrtf(var + BN_EPS);
        ss[t] = sc;
        ss[128 + t] = beta[t] - mu * sc;
    }
}

// ---------------- pool: per-graph sum of BN(y bf16) -> bf16 pooled -----------
__global__ __launch_bounds__(128) void pool_k(const unsigned short* __restrict__ y0,
                                              const unsigned short* __restrict__ y1,
                                              const unsigned short* __restrict__ y2,
                                              const float* __restrict__ ss,
                                              const int* __restrict__ batch, unsigned short* __restrict__ pb) {
    int g = blockIdx.x;
    int lo = 0, hi = NN;
    while (lo < hi) { int mid = (lo + hi) >> 1; if (batch[mid] < g) lo = mid + 1; else hi = mid; }
    int s = lo;
    lo = s; hi = NN;
    while (lo < hi) { int mid = (lo + hi) >> 1; if (batch[mid] < g + 1) lo = mid + 1; else hi = mid; }
    int e = lo;
    int t = threadIdx.x;
    float sc0 = ss[t],       sh0 = ss[128 + t];
    float sc1 = ss[256 + t], sh1 = ss[384 + t];
    float sc2 = ss[512 + t], sh2 = ss[640 + t];
    float a0 = 0.f, a1 = 0.f, a2 = 0.f;
    for (int n = s; n < e; ++n) {
        a0 += fmaf(bf2f((unsigned int)y0[(size_t)n * 128 + t]), sc0, sh0);
        a1 += fmaf(bf2f((unsigned int)y1[(size_t)n * 128 + t]), sc1, sh1);
        a2 += fmaf(bf2f((unsigned int)y2[(size_t)n * 128 + t]), sc2, sh2);
    }
    pb[(size_t)g * 384 + t]       = f2bf(a0);
    pb[(size_t)g * 384 + t + 128] = f2bf(a1);
    pb[(size_t)g * 384 + t + 256] = f2bf(a2);
}

// ---------------- proj MFMA GEMM: [512,384]bf16 @ Wpt[c][384k] + bias --------
__global__ __launch_bounds__(256) void projm_k(const unsigned short* __restrict__ A,
                                               const unsigned short* __restrict__ Wpt,
                                               const float* __restrict__ bias,
                                               unsigned short* __restrict__ outb,
                                               float* __restrict__ outf) {
    __shared__ __align__(16) unsigned short sW[128 * 136];
    const int tid = threadIdx.x;
    const int col_off = blockIdx.y * 128;
    const int w = tid >> 6, l = tid & 63;
    const int lr = l & 15, lk = l >> 4;
    const int row0 = blockIdx.x * 64 + w * 16;
    f32x4 acc[8] = {};
    for (int kk = 0; kk < 3; ++kk) {
        __syncthreads();
        for (int ch = tid; ch < 2048; ch += 256) {
            int c = ch >> 4, i = ch & 15;
            *(uint4*)(sW + c * 136 + i * 8) = *(const uint4*)(Wpt + (size_t)(col_off + c) * 384 + kk * 128 + i * 8);
        }
        const unsigned short* ap = A + (size_t)(row0 + lr) * 384 + kk * 128 + lk * 8;
        short8 af0 = *(const short8*)(ap);
        short8 af1 = *(const short8*)(ap + 32);
        short8 af2 = *(const short8*)(ap + 64);
        short8 af3 = *(const short8*)(ap + 96);
        __syncthreads();
        #pragma unroll
        for (int c = 0; c < 8; ++c) {
            const unsigned short* wp = sW + (c * 16 + lr) * 136 + lk * 8;
            short8 wf0 = *(const short8*)(wp);
            short8 wf1 = *(const short8*)(wp + 32);
            short8 wf2 = *(const short8*)(wp + 64);
            short8 wf3 = *(const short8*)(wp + 96);
            acc[c] = __builtin_amdgcn_mfma_f32_16x16x32_bf16(af0, wf0, acc[c], 0, 0, 0);
            acc[c] = __builtin_amdgcn_mfma_f32_16x16x32_bf16(af1, wf1, acc[c], 0, 0, 0);
            acc[c] = __builtin_amdgcn_mfma_f32_16x16x32_bf16(af2, wf2, acc[c], 0, 0, 0);
            acc[c] = __builtin_amdgcn_mfma_f32_16x16x32_bf16(af3, wf3, acc[c], 0, 0, 0);
        }
    }
    const int drow = row0 + lk * 4;
    #pragma unroll
    for (int c = 0; c < 8; ++c) {
        int col = col_off + c * 16 + lr;
        float b = bias[col];
        #pragma unroll
        for (int r = 0; r < 4; ++r) {
            float v = acc[c][r] + b;
            if (outb) outb[(size_t)(drow + r) * 384 + col] = f2bf(fmaxf(v, 0.f));
            else      outf[(size_t)(drow + r) * 384 + col] = v;
        }
    }
}

extern "C" void kernel_launch(void* const* d_in, const int* in_sizes, int n_in,
                              void* d_out, int out_size, void* d_ws, size_t ws_size,
                              hipStream_t stream) {
    const float* x     = (const float*)d_in[0];
    const int*   ei    = (const int*)d_in[1];
    const int*   srcI  = ei;
    const int*   dstI  = ei + NE;
    const int*   batch = (const int*)d_in[2];
    const float* W1    = (const float*)d_in[3];
    const float* b1    = (const float*)d_in[4];
    const float* W2    = (const float*)d_in[5];
    const float* b2    = (const float*)d_in[6];
    const float* gamma = (const float*)d_in[7];
    const float* beta  = (const float*)d_in[8];
    const float* Wp1   = (const float*)d_in[9];
    const float* bp1   = (const float*)d_in[10];
    const float* Wp2   = (const float*)d_in[11];
    const float* bp2   = (const float*)d_in[12];
    float* out = (float*)d_out;

    float* ssbuf  = (float*)d_ws;                     // 3*256
    float* part   = ssbuf + 3 * 256;                  // NRED1*256
    float* scr    = part + NRED1 * 256;               // 3 * NBLK_MLP * 256
    int*   cnt    = (int*)(scr + 3 * NBLK_MLP * 256); // N
    int*   bcur   = cnt + NN;                         // NBKT
    unsigned int* staging = (unsigned int*)(bcur + NBKT + 4);   // NBKT*BCAP
    unsigned short* ell  = (unsigned short*)(staging + (size_t)NBKT * BCAP); // N*PAD
    unsigned short* xb   = ell + (size_t)NN * PAD;             // N*128
    unsigned short* yb0  = xb + (size_t)NN * 128;
    unsigned short* yb1  = yb0 + (size_t)NN * 128;
    unsigned short* yb2  = yb1 + (size_t)NN * 128;
    unsigned short* Wt   = yb2 + (size_t)NN * 128;             // 6*16384
    unsigned short* Wpt  = Wt + 6 * 16384;                     // 2*147456
    unsigned short* pb   = Wpt + 2 * 147456;                   // G*384
    unsigned short* z1b  = pb + (size_t)GG * 384;              // G*384

    conv_k<<<NTRB + 1024, 256, 0, stream>>>(x, W1, W2, Wp1, Wp2, xb, Wt, Wpt, bcur);
    bucket_k<<<256, 256, 0, stream>>>(srcI, dstI, bcur, staging);
    ellfill_k<<<NBKT, 256, 0, stream>>>(bcur, staging, cnt, ell);

    unsigned short* ybufs[3] = {yb0, yb1, yb2};
    for (int l = 0; l < 3; ++l) {
        const unsigned short* h = (l == 0) ? xb : ybufs[l - 1];
        const float* ssl        = (l == 0) ? nullptr : (ssbuf + (l - 1) * 256);

        layer_k<<<NBLK_MLP, 256, 0, stream>>>(cnt, ell, h, ssl,
                                              Wt + (size_t)(2 * l) * 16384,
                                              b1 + l * 128, b2 + l * 128,
                                              ybufs[l], scr + (size_t)l * NBLK_MLP * 256);
        bnr1_k<<<NRED1, 256, 0, stream>>>(scr + (size_t)l * NBLK_MLP * 256, part);
        bnr2_k<<<1, 1024, 0, stream>>>(part, gamma + l * 128, beta + l * 128, ssbuf + l * 256);
    }

    pool_k<<<GG, 128, 0, stream>>>(yb0, yb1, yb2, ssbuf, batch, pb);
    {
        dim3 gp(8, 3);
        projm_k<<<gp, 256, 0, stream>>>(pb, Wpt, bp1, z1b, nullptr);
        projm_k<<<gp, 256, 0, stream>>>(z1b, Wpt + 147456, bp2, nullptr, out);
    }
}

// Round 14
// 444.044 us; speedup vs baseline: 1.1391x; 1.1391x over previous
//
#include <hip/hip_runtime.h>

#define NN 50000
#define NE 1600000
#define GG 512
#define PAD 96
#define NBKT 196
#define BCAP 12288
#define CHUNK 6250
#define NBLK_MLP 782
#define NRED1 196
#define BN_EPS 1e-5f
#define XCONV_TOT (NN * 32)
#define NTRB 96   // transpose blocks: 24 (W) + 72 (Wp)

typedef __attribute__((ext_vector_type(8))) short short8;
typedef __attribute__((ext_vector_type(4))) float f32x4;

__device__ __forceinline__ unsigned short f2bf(float x) {
    unsigned int u = __builtin_bit_cast(unsigned int, x);
    return (unsigned short)((u + 0x7FFFu + ((u >> 16) & 1u)) >> 16);
}
__device__ __forceinline__ float bf2f(unsigned int b) {
    return __builtin_bit_cast(float, b << 16);
}

// ---------------- phase 1: bucket edges by dst>>8 into staging ---------------
__global__ __launch_bounds__(256) void bucket_k(const int* __restrict__ src, const int* __restrict__ dst,
                                                int* __restrict__ bcur, unsigned int* __restrict__ staging) {
    __shared__ int hist[NBKT];
    __shared__ int curs[NBKT];
    const int t = threadIdx.x;
    if (t < NBKT) hist[t] = 0;
    __syncthreads();
    const int e0 = blockIdx.x * CHUNK;
    const int e1 = e0 + CHUNK;
    for (int e = e0 + t; e < e1; e += 256) atomicAdd(&hist[dst[e] >> 8], 1);
    __syncthreads();
    if (t < NBKT) {
        int c = hist[t];
        curs[t] = (c > 0) ? atomicAdd(&bcur[t], c) : 0;
    }
    __syncthreads();
    for (int e = e0 + t; e < e1; e += 256) {
        int d = dst[e];
        int b = d >> 8;
        int pos = atomicAdd(&curs[b], 1);
        staging[(size_t)b * BCAP + pos] = (unsigned int)(d & 255) | ((unsigned int)src[e] << 8);
    }
}

// ---------------- phase 2: bucket -> LDS ELL tile -> coalesced global --------
__global__ __launch_bounds__(256) void ellfill_k(const int* __restrict__ bcur,
                                                 const unsigned int* __restrict__ staging,
                                                 int* __restrict__ cnt, unsigned short* __restrict__ ell) {
    __shared__ unsigned short lell[256 * PAD]; // 48 KB
    __shared__ int lcnt[256];
    const int b = blockIdx.x, t = threadIdx.x;
    lcnt[t] = 0;
    __syncthreads();
    const int tot = bcur[b];
    const unsigned int* sg = staging + (size_t)b * BCAP;
    for (int i = t; i < tot; i += 256) {
        unsigned int v = sg[i];
        int r = v & 255;
        int p = atomicAdd(&lcnt[r], 1);
        lell[r * PAD + p] = (unsigned short)(v >> 8);
    }
    __syncthreads();
    const int n0 = b << 8;
    const int nrows = min(256, NN - n0);
    for (int i = t; i < nrows * 12; i += 256) {
        int r = i / 12, q = i % 12;
        *(uint4*)(ell + (size_t)(n0 + r) * PAD + q * 8) = *(const uint4*)(lell + r * PAD + q * 8);
    }
    if (t < nrows) cnt[n0 + t] = lcnt[t];
}

// ---------------- conversions: tiled W/Wp transposes + x->bf16 + bcur zero ---
__global__ __launch_bounds__(256) void conv_k(const float* __restrict__ x,
                                              const float* __restrict__ W1, const float* __restrict__ W2,
                                              const float* __restrict__ Wp1, const float* __restrict__ Wp2,
                                              unsigned short* __restrict__ xb, unsigned short* __restrict__ Wt,
                                              unsigned short* __restrict__ Wpt, int* __restrict__ bcur) {
    const int b = blockIdx.x, tid = threadIdx.x;
    if (b < NTRB) {
        __shared__ float tile[64 * 65];
        const float* S;
        unsigned short* D;
        int srcW, dstW, k0, c0;
        if (b < 24) {                       // W: 6 mats x (2x2 64-tiles), 128x128
            int mat = b >> 2, t = b & 3;
            S = ((mat & 1) ? W2 : W1) + (size_t)(mat >> 1) * 16384;
            D = Wt + (size_t)mat * 16384;
            srcW = 128; dstW = 128;
            k0 = (t >> 1) * 64; c0 = (t & 1) * 64;
        } else {                            // Wp: 2 mats x (6x6 64-tiles), 384x384
            int bb = b - 24;
            int mat = bb / 36, t = bb % 36;
            S = mat ? Wp2 : Wp1;
            D = Wpt + (size_t)mat * 147456;
            srcW = 384; dstW = 384;
            k0 = (t / 6) * 64; c0 = (t % 6) * 64;
        }
        for (int idx = tid; idx < 4096; idx += 256) {
            int r = idx >> 6, c = idx & 63;
            tile[r * 65 + c] = S[(size_t)(k0 + r) * srcW + c0 + c];
        }
        __syncthreads();
        for (int idx = tid; idx < 4096; idx += 256) {
            int r = idx >> 6, c = idx & 63;   // out row r = c-dim, out col c = k-dim
            D[(size_t)(c0 + r) * dstW + k0 + c] = f2bf(tile[c * 65 + r]);
        }
    } else {
        int i = (b - NTRB) * 256 + tid;
        if (i < NBKT) bcur[i] = 0;
        const int stp = (gridDim.x - NTRB) * 256;
        for (; i < XCONV_TOT; i += stp) {
            float4 v = ((const float4*)x)[i];
            uint2 pk;
            pk.x = (unsigned int)f2bf(v.x) | ((unsigned int)f2bf(v.y) << 16);
            pk.y = (unsigned int)f2bf(v.z) | ((unsigned int)f2bf(v.w) << 16);
            ((uint2*)xb)[i] = pk;
        }
    }
}

// ---------------- aggregation (R12/R9 form): 16 lanes/node, full 128 cols ----
__global__ __launch_bounds__(256) void agg_k(const int* __restrict__ cnt, const unsigned short* __restrict__ ell,
                                             const unsigned short* __restrict__ h, const float* __restrict__ ss,
                                             unsigned short* __restrict__ m) {
    int gid = blockIdx.x * 256 + threadIdx.x;
    int n = gid >> 4, l = gid & 15;
    if (n >= NN) return;
    float sc[8], sh[8];
    #pragma unroll
    for (int j = 0; j < 8; ++j) { sc[j] = 1.f; sh[j] = 0.f; }
    if (ss) {
        #pragma unroll
        for (int j = 0; j < 8; ++j) { sc[j] = ss[l * 8 + j]; sh[j] = ss[128 + l * 8 + j]; }
    }
    int e = cnt[n];
    const unsigned short* row = ell + (size_t)n * PAD;
    float acc[8];
    {
        uint4 q = *(const uint4*)(h + (size_t)n * 128 + l * 8);
        unsigned int qq[4] = {q.x, q.y, q.z, q.w};
        #pragma unroll
        for (int j = 0; j < 4; ++j) {
            acc[2 * j]     = bf2f(qq[j] & 0xffffu) * sc[2 * j];
            acc[2 * j + 1] = bf2f(qq[j] >> 16)     * sc[2 * j + 1];
        }
    }
    int i = 0;
    for (; i + 8 <= e; i += 8) {
        uint4 ip = *(const uint4*)(row + i);
        int s0 = ip.x & 0xffff, s1 = ip.x >> 16, s2 = ip.y & 0xffff, s3 = ip.y >> 16;
        int s4 = ip.z & 0xffff, s5 = ip.z >> 16, s6 = ip.w & 0xffff, s7 = ip.w >> 16;
        uint4 q0 = *(const uint4*)(h + (size_t)s0 * 128 + l * 8);
        uint4 q1 = *(const uint4*)(h + (size_t)s1 * 128 + l * 8);
        uint4 q2 = *(const uint4*)(h + (size_t)s2 * 128 + l * 8);
        uint4 q3 = *(const uint4*)(h + (size_t)s3 * 128 + l * 8);
        uint4 q4 = *(const uint4*)(h + (size_t)s4 * 128 + l * 8);
        uint4 q5 = *(const uint4*)(h + (size_t)s5 * 128 + l * 8);
        uint4 q6 = *(const uint4*)(h + (size_t)s6 * 128 + l * 8);
        uint4 q7 = *(const uint4*)(h + (size_t)s7 * 128 + l * 8);
        unsigned int a0[4] = {q0.x, q0.y, q0.z, q0.w};
        unsigned int a1[4] = {q1.x, q1.y, q1.z, q1.w};
        unsigned int a2[4] = {q2.x, q2.y, q2.z, q2.w};
        unsigned int a3[4] = {q3.x, q3.y, q3.z, q3.w};
        unsigned int a4[4] = {q4.x, q4.y, q4.z, q4.w};
        unsigned int a5[4] = {q5.x, q5.y, q5.z, q5.w};
        unsigned int a6[4] = {q6.x, q6.y, q6.z, q6.w};
        unsigned int a7[4] = {q7.x, q7.y, q7.z, q7.w};
        #pragma unroll
        for (int j = 0; j < 4; ++j) {
            float t0 = bf2f(a0[j] & 0xffffu) + bf2f(a1[j] & 0xffffu);
            float t1 = bf2f(a2[j] & 0xffffu) + bf2f(a3[j] & 0xffffu);
            float t2 = bf2f(a4[j] & 0xffffu) + bf2f(a5[j] & 0xffffu);
            float t3 = bf2f(a6[j] & 0xffffu) + bf2f(a7[j] & 0xffffu);
            acc[2*j] = fmaf((t0 + t1) + (t2 + t3), sc[2*j], acc[2*j]);
            float u0 = bf2f(a0[j] >> 16) + bf2f(a1[j] >> 16);
            float u1 = bf2f(a2[j] >> 16) + bf2f(a3[j] >> 16);
            float u2 = bf2f(a4[j] >> 16) + bf2f(a5[j] >> 16);
            float u3 = bf2f(a6[j] >> 16) + bf2f(a7[j] >> 16);
            acc[2*j+1] = fmaf((u0 + u1) + (u2 + u3), sc[2*j+1], acc[2*j+1]);
        }
    }
    for (; i < e; ++i) {
        int s0 = row[i];
        uint4 q = *(const uint4*)(h + (size_t)s0 * 128 + l * 8);
        unsigned int qq[4] = {q.x, q.y, q.z, q.w};
        #pragma unroll
        for (int j = 0; j < 4; ++j) {
            acc[2*j]   = fmaf(bf2f(qq[j] & 0xffffu), sc[2*j],   acc[2*j]);
            acc[2*j+1] = fmaf(bf2f(qq[j] >> 16),     sc[2*j+1], acc[2*j+1]);
        }
    }
    float fe = (float)(e + 1);
    #pragma unroll
    for (int j = 0; j < 8; ++j) acc[j] = fmaf(fe, sh[j], acc[j]);
    uint4 pk;
    pk.x = (unsigned int)f2bf(acc[0]) | ((unsigned int)f2bf(acc[1]) << 16);
    pk.y = (unsigned int)f2bf(acc[2]) | ((unsigned int)f2bf(acc[3]) << 16);
    pk.z = (unsigned int)f2bf(acc[4]) | ((unsigned int)f2bf(acc[5]) << 16);
    pk.w = (unsigned int)f2bf(acc[6]) | ((unsigned int)f2bf(acc[7]) << 16);
    *(uint4*)(m + (size_t)n * 128 + l * 8) = pk;
}

// ---------------- fused MLP: y = relu(relu(m@W1+b1)@W2+b2), bf16 out ---------
__global__ __launch_bounds__(256) void mlp_k(const unsigned short* __restrict__ A,
                                             const unsigned short* __restrict__ Wt,
                                             const float* __restrict__ bias1,
                                             const float* __restrict__ bias2,
                                             unsigned short* __restrict__ yb,
                                             float* __restrict__ scr) {
    __shared__ __align__(16) unsigned short sW[128 * 136];  // 34 KB
    __shared__ __align__(16) unsigned short sT[64 * 136];   // 17 KB (reused as f32 sred)
    float* sred = (float*)sT;
    const int tid = threadIdx.x;
    for (int ch = tid; ch < 2048; ch += 256) {
        int c = ch >> 4, i = ch & 15;
        *(uint4*)(sW + c * 136 + i * 8) = *(const uint4*)(Wt + c * 128 + i * 8);
    }
    const int w = tid >> 6, l = tid & 63;
    const int lr = l & 15, lk = l >> 4;
    const int row0 = blockIdx.x * 64 + w * 16;
    const unsigned short* ap = A + (size_t)(row0 + lr) * 128 + lk * 8;
    short8 af0 = *(const short8*)(ap);
    short8 af1 = *(const short8*)(ap + 32);
    short8 af2 = *(const short8*)(ap + 64);
    short8 af3 = *(const short8*)(ap + 96);
    f32x4 acc[8] = {};
    __syncthreads();
    #pragma unroll
    for (int c = 0; c < 8; ++c) {
        const unsigned short* wp = sW + (c * 16 + lr) * 136 + lk * 8;
        short8 wf0 = *(const short8*)(wp);
        short8 wf1 = *(const short8*)(wp + 32);
        short8 wf2 = *(const short8*)(wp + 64);
        short8 wf3 = *(const short8*)(wp + 96);
        acc[c] = __builtin_amdgcn_mfma_f32_16x16x32_bf16(af0, wf0, acc[c], 0, 0, 0);
        acc[c] = __builtin_amdgcn_mfma_f32_16x16x32_bf16(af1, wf1, acc[c], 0, 0, 0);
        acc[c] = __builtin_amdgcn_mfma_f32_16x16x32_bf16(af2, wf2, acc[c], 0, 0, 0);
        acc[c] = __builtin_amdgcn_mfma_f32_16x16x32_bf16(af3, wf3, acc[c], 0, 0, 0);
    }
    const int lrow = w * 16 + lk * 4;
    #pragma unroll
    for (int c = 0; c < 8; ++c) {
        int col = c * 16 + lr;
        float b = bias1[col];
        #pragma unroll
        for (int r = 0; r < 4; ++r) {
            float v = fmaxf(acc[c][r] + b, 0.f);
            sT[(lrow + r) * 136 + col] = f2bf(v);
        }
    }
    __syncthreads();
    for (int ch = tid; ch < 2048; ch += 256) {
        int c = ch >> 4, i = ch & 15;
        *(uint4*)(sW + c * 136 + i * 8) = *(const uint4*)(Wt + 16384 + c * 128 + i * 8);
    }
    const unsigned short* tp = sT + (w * 16 + lr) * 136 + lk * 8;
    short8 bf0 = *(const short8*)(tp);
    short8 bf1 = *(const short8*)(tp + 32);
    short8 bf2_ = *(const short8*)(tp + 64);
    short8 bf3 = *(const short8*)(tp + 96);
    f32x4 acc2[8] = {};
    __syncthreads();       // after this barrier every wave has read its sT rows
    #pragma unroll
    for (int c = 0; c < 8; ++c) {
        const unsigned short* wp = sW + (c * 16 + lr) * 136 + lk * 8;
        short8 wf0 = *(const short8*)(wp);
        short8 wf1 = *(const short8*)(wp + 32);
        short8 wf2 = *(const short8*)(wp + 64);
        short8 wf3 = *(const short8*)(wp + 96);
        acc2[c] = __builtin_amdgcn_mfma_f32_16x16x32_bf16(bf0, wf0, acc2[c], 0, 0, 0);
        acc2[c] = __builtin_amdgcn_mfma_f32_16x16x32_bf16(bf1, wf1, acc2[c], 0, 0, 0);
        acc2[c] = __builtin_amdgcn_mfma_f32_16x16x32_bf16(bf2_, wf2, acc2[c], 0, 0, 0);
        acc2[c] = __builtin_amdgcn_mfma_f32_16x16x32_bf16(bf3, wf3, acc2[c], 0, 0, 0);
    }
    const int drow = row0 + lk * 4;
    #pragma unroll
    for (int c = 0; c < 8; ++c) {
        int col = c * 16 + lr;
        float b = bias2[col];
        float s1 = 0.f, s2 = 0.f;
        #pragma unroll
        for (int r = 0; r < 4; ++r) {
            int grow = drow + r;
            float v = fmaxf(acc2[c][r] + b, 0.f);
            if (grow < NN) {
                yb[(size_t)grow * 128 + col] = f2bf(v);
                s1 += v;
                s2 += v * v;
            }
        }
        s1 += __shfl_xor(s1, 16); s1 += __shfl_xor(s1, 32);
        s2 += __shfl_xor(s2, 16); s2 += __shfl_xor(s2, 32);
        if (lk == 0) {
            sred[((w * 16 + lr) * 8 + c) * 2 + 0] = s1;   // aliased onto sT: safe post-barrier
            sred[((w * 16 + lr) * 8 + c) * 2 + 1] = s2;
        }
    }
    __syncthreads();
    int st = tid & 1, c = (tid >> 1) & 7, lr2 = tid >> 4;
    float t = 0.f;
    #pragma unroll
    for (int w2 = 0; w2 < 4; ++w2) t += sred[((w2 * 16 + lr2) * 8 + c) * 2 + st];
    scr[(size_t)blockIdx.x * 256 + st * 128 + c * 16 + lr2] = t;
}

// ---------------- BN reduce stage 1: scr[NBLK_MLP][256] -> part[NRED1][256] --
__global__ __launch_bounds__(256) void bnr1_k(const float* __restrict__ scr, float* __restrict__ part) {
    int b = blockIdx.x, d = threadIdx.x;
    float a = 0.f;
    for (int r = b; r < NBLK_MLP; r += NRED1) a += scr[(size_t)r * 256 + d];
    part[(size_t)b * 256 + d] = a;
}

// ---------------- BN reduce stage 2 + finalize -------------------------------
__global__ __launch_bounds__(1024) void bnr2_k(const float* __restrict__ part, const float* __restrict__ gamma,
                                               const float* __restrict__ beta, float* __restrict__ ss) {
    __shared__ float red[4][256];
    int t = threadIdx.x, q = t >> 8, d = t & 255;
    float a = 0.f;
    for (int r = q; r < NRED1; r += 4) a += part[(size_t)r * 256 + d];
    red[q][d] = a;
    __syncthreads();
    if (t < 256) red[0][t] = red[0][t] + red[1][t] + red[2][t] + red[3][t];
    __syncthreads();
    if (t < 128) {
        float mu = red[0][t] * (1.0f / NN);
        float var = red[0][128 + t] * (1.0f / NN) - mu * mu;
        float sc = gamma[t] * rsqrtf(var + BN_EPS);
        ss[t] = sc;
        ss[128 + t] = beta[t] - mu * sc;
    }
}

// ---------------- pool: per-graph sum of BN(y bf16) -> bf16 pooled -----------
__global__ __launch_bounds__(128) void pool_k(const unsigned short* __restrict__ y0,
                                              const unsigned short* __restrict__ y1,
                                              const unsigned short* __restrict__ y2,
                                              const float* __restrict__ ss,
                                              const int* __restrict__ batch, unsigned short* __restrict__ pb) {
    int g = blockIdx.x;
    int lo = 0, hi = NN;
    while (lo < hi) { int mid = (lo + hi) >> 1; if (batch[mid] < g) lo = mid + 1; else hi = mid; }
    int s = lo;
    lo = s; hi = NN;
    while (lo < hi) { int mid = (lo + hi) >> 1; if (batch[mid] < g + 1) lo = mid + 1; else hi = mid; }
    int e = lo;
    int t = threadIdx.x;
    float sc0 = ss[t],       sh0 = ss[128 + t];
    float sc1 = ss[256 + t], sh1 = ss[384 + t];
    float sc2 = ss[512 + t], sh2 = ss[640 + t];
    float a0 = 0.f, a1 = 0.f, a2 = 0.f;
    for (int n = s; n < e; ++n) {
        a0 += fmaf(bf2f((unsigned int)y0[(size_t)n * 128 + t]), sc0, sh0);
        a1 += fmaf(bf2f((unsigned int)y1[(size_t)n * 128 + t]), sc1, sh1);
        a2 += fmaf(bf2f((unsigned int)y2[(size_t)n * 128 + t]), sc2, sh2);
    }
    pb[(size_t)g * 384 + t]       = f2bf(a0);
    pb[(size_t)g * 384 + t + 128] = f2bf(a1);
    pb[(size_t)g * 384 + t + 256] = f2bf(a2);
}

// ---------------- proj MFMA GEMM: [512,384]bf16 @ Wpt[c][384k] + bias --------
__global__ __launch_bounds__(256) void projm_k(const unsigned short* __restrict__ A,
                                               const unsigned short* __restrict__ Wpt,
                                               const float* __restrict__ bias,
                                               unsigned short* __restrict__ outb,
                                               float* __restrict__ outf) {
    __shared__ __align__(16) unsigned short sW[128 * 136];
    const int tid = threadIdx.x;
    const int col_off = blockIdx.y * 128;
    const int w = tid >> 6, l = tid & 63;
    const int lr = l & 15, lk = l >> 4;
    const int row0 = blockIdx.x * 64 + w * 16;
    f32x4 acc[8] = {};
    for (int kk = 0; kk < 3; ++kk) {
        __syncthreads();
        for (int ch = tid; ch < 2048; ch += 256) {
            int c = ch >> 4, i = ch & 15;
            *(uint4*)(sW + c * 136 + i * 8) = *(const uint4*)(Wpt + (size_t)(col_off + c) * 384 + kk * 128 + i * 8);
        }
        const unsigned short* ap = A + (size_t)(row0 + lr) * 384 + kk * 128 + lk * 8;
        short8 af0 = *(const short8*)(ap);
        short8 af1 = *(const short8*)(ap + 32);
        short8 af2 = *(const short8*)(ap + 64);
        short8 af3 = *(const short8*)(ap + 96);
        __syncthreads();
        #pragma unroll
        for (int c = 0; c < 8; ++c) {
            const unsigned short* wp = sW + (c * 16 + lr) * 136 + lk * 8;
            short8 wf0 = *(const short8*)(wp);
            short8 wf1 = *(const short8*)(wp + 32);
            short8 wf2 = *(const short8*)(wp + 64);
            short8 wf3 = *(const short8*)(wp + 96);
            acc[c] = __builtin_amdgcn_mfma_f32_16x16x32_bf16(af0, wf0, acc[c], 0, 0, 0);
            acc[c] = __builtin_amdgcn_mfma_f32_16x16x32_bf16(af1, wf1, acc[c], 0, 0, 0);
            acc[c] = __builtin_amdgcn_mfma_f32_16x16x32_bf16(af2, wf2, acc[c], 0, 0, 0);
            acc[c] = __builtin_amdgcn_mfma_f32_16x16x32_bf16(af3, wf3, acc[c], 0, 0, 0);
        }
    }
    const int drow = row0 + lk * 4;
    #pragma unroll
    for (int c = 0; c < 8; ++c) {
        int col = col_off + c * 16 + lr;
        float b = bias[col];
        #pragma unroll
        for (int r = 0; r < 4; ++r) {
            float v = acc[c][r] + b;
            if (outb) outb[(size_t)(drow + r) * 384 + col] = f2bf(fmaxf(v, 0.f));
            else      outf[(size_t)(drow + r) * 384 + col] = v;
        }
    }
}

extern "C" void kernel_launch(void* const* d_in, const int* in_sizes, int n_in,
                              void* d_out, int out_size, void* d_ws, size_t ws_size,
                              hipStream_t stream) {
    const float* x     = (const float*)d_in[0];
    const int*   ei    = (const int*)d_in[1];
    const int*   srcI  = ei;
    const int*   dstI  = ei + NE;
    const int*   batch = (const int*)d_in[2];
    const float* W1    = (const float*)d_in[3];
    const float* b1    = (const float*)d_in[4];
    const float* W2    = (const float*)d_in[5];
    const float* b2    = (const float*)d_in[6];
    const float* gamma = (const float*)d_in[7];
    const float* beta  = (const float*)d_in[8];
    const float* Wp1   = (const float*)d_in[9];
    const float* bp1   = (const float*)d_in[10];
    const float* Wp2   = (const float*)d_in[11];
    const float* bp2   = (const float*)d_in[12];
    float* out = (float*)d_out;

    float* ssbuf  = (float*)d_ws;                     // 3*256
    float* part   = ssbuf + 3 * 256;                  // NRED1*256
    float* scr    = part + NRED1 * 256;               // 3 * NBLK_MLP * 256
    int*   cnt    = (int*)(scr + 3 * NBLK_MLP * 256); // N
    int*   bcur   = cnt + NN;                         // NBKT
    unsigned int* staging = (unsigned int*)(bcur + NBKT + 4);   // NBKT*BCAP
    unsigned short* ell  = (unsigned short*)(staging + (size_t)NBKT * BCAP); // N*PAD
    unsigned short* xb   = ell + (size_t)NN * PAD;             // N*128
    unsigned short* yb0  = xb + (size_t)NN * 128;
    unsigned short* yb1  = yb0 + (size_t)NN * 128;
    unsigned short* yb2  = yb1 + (size_t)NN * 128;
    unsigned short* m_bf = yb2 + (size_t)NN * 128;             // N*128
    unsigned short* Wt   = m_bf + (size_t)NN * 128;            // 6*16384
    unsigned short* Wpt  = Wt + 6 * 16384;                     // 2*147456
    unsigned short* pb   = Wpt + 2 * 147456;                   // G*384
    unsigned short* z1b  = pb + (size_t)GG * 384;              // G*384

    conv_k<<<NTRB + 1024, 256, 0, stream>>>(x, W1, W2, Wp1, Wp2, xb, Wt, Wpt, bcur);
    bucket_k<<<256, 256, 0, stream>>>(srcI, dstI, bcur, staging);
    ellfill_k<<<NBKT, 256, 0, stream>>>(bcur, staging, cnt, ell);

    unsigned short* ybufs[3] = {yb0, yb1, yb2};
    for (int l = 0; l < 3; ++l) {
        const unsigned short* h = (l == 0) ? xb : ybufs[l - 1];
        const float* ssl        = (l == 0) ? nullptr : (ssbuf + (l - 1) * 256);

        agg_k<<<3125, 256, 0, stream>>>(cnt, ell, h, ssl, m_bf);
        mlp_k<<<NBLK_MLP, 256, 0, stream>>>(m_bf, Wt + (size_t)(2 * l) * 16384,
                                            b1 + l * 128, b2 + l * 128,
                                            ybufs[l], scr + (size_t)l * NBLK_MLP * 256);
        bnr1_k<<<NRED1, 256, 0, stream>>>(scr + (size_t)l * NBLK_MLP * 256, part);
        bnr2_k<<<1, 1024, 0, stream>>>(part, gamma + l * 128, beta + l * 128, ssbuf + l * 256);
    }

    pool_k<<<GG, 128, 0, stream>>>(yb0, yb1, yb2, ssbuf, batch, pb);
    {
        dim3 gp(8, 3);
        projm_k<<<gp, 256, 0, stream>>>(pb, Wpt, bp1, z1b, nullptr);
        projm_k<<<gp, 256, 0, stream>>>(z1b, Wpt + 147456, bp2, nullptr, out);
    }
}